// Round 6
// baseline (69.298 us; speedup 1.0000x reference)
//
#include <hip/hip_runtime.h>
#include <hip/hip_bf16.h>

typedef __bf16 bf16x8 __attribute__((ext_vector_type(8)));
typedef float floatx4 __attribute__((ext_vector_type(4)));

#define BM 256
#define BN 128
#define BK 64
#define A_TILE (BM * BK)   // 16384 ushorts = 32 KB
#define B_TILE (BN * BK)   // 8192 ushorts  = 16 KB
#define EPS 1e-5f

// ---------------- f32 -> bf16 conversion (vectorized, grid-stride) ----------
__global__ void cvt_f32_to_bf16(const float* __restrict__ in,
                                ushort* __restrict__ out, int n4) {
    int i = blockIdx.x * blockDim.x + threadIdx.x;
    int stride = gridDim.x * blockDim.x;
    for (; i < n4; i += stride) {
        float4 v = reinterpret_cast<const float4*>(in)[i];
        ushort4 o;
        o.x = __builtin_bit_cast(unsigned short, __float2bfloat16(v.x));
        o.y = __builtin_bit_cast(unsigned short, __float2bfloat16(v.y));
        o.z = __builtin_bit_cast(unsigned short, __float2bfloat16(v.z));
        o.w = __builtin_bit_cast(unsigned short, __float2bfloat16(v.w));
        reinterpret_cast<ushort4*>(out)[i] = o;
    }
}

// ---------------- fold BN+scale into per-column alpha/bias ------------------
__global__ void bn_fold(const float* __restrict__ scale,
                        const float* __restrict__ mean,
                        const float* __restrict__ var,
                        const float* __restrict__ gamma,
                        const float* __restrict__ beta,
                        float* __restrict__ alpha,
                        float* __restrict__ bias, int n) {
    int i = blockIdx.x * blockDim.x + threadIdx.x;
    if (i < n) {
        float rs = rsqrtf(var[i] + EPS);
        float g = gamma[i] * rs;
        alpha[i] = scale[i] * g;
        bias[i]  = beta[i] - mean[i] * g;
    }
}

__device__ __forceinline__ void gload_lds16(const ushort* g, ushort* l) {
    __builtin_amdgcn_global_load_lds(
        (const __attribute__((address_space(1))) void*)g,
        (__attribute__((address_space(3))) void*)l, 16, 0, 0);
}

// ---------------- bf16 MFMA GEMM: 256x128 tile, BK=64 ----------------------
// 3 LDS buffers, depth-2 staging (target = 2 ahead, never the read buffer),
// cross-phase fragment pipelining so ds_read issue overlaps MFMA:
//
// iter kt (cur=kt%3):            regs hold frag(kt,0)
//   B1 barrier                   // all waves done reading tile kt-1
//   STAGE(kt+2 -> buf[(kt+2)%3]) // held tile kt-1; safe. outstanding 6->12
//   issue ds_read frag(kt,1)     // from cur
//   MFMA frag(kt,0)              // no wait (regs ready); hides the ds_reads
//   s_waitcnt vmcnt(6)           // tile kt+1 landed (own loads)
//   B2 barrier                   // all waves' tile kt+1 landed
//   issue ds_read frag(kt+1,0)   // from buf[(kt+1)%3]
//   MFMA frag(kt,1)              // compiler lgkm-guards frag(kt,1) only
//
// R4 diagnosis: the old {all reads -> lgkmcnt(0) -> barrier -> all MFMA}
// lockstep ADDED LDS-read time (~1540 cyc/iter) to MFMA time (~1030) ->
// 3712 cyc/iter measured. This structure overlaps them.
//
// LDS swizzle (T2, rule #21 both-sides): phys chunk = logical chunk ^ (row&7),
// pre-swizzled on the global source, same XOR on reads. R2: conflicts = 0.
__global__ __launch_bounds__(512, 2) void gemm_bf16_bn(
    const ushort* __restrict__ A,   // [M][K] bf16 bits
    const ushort* __restrict__ B,   // [N][K] bf16 bits
    const float* __restrict__ alpha,
    const float* __restrict__ bias,
    float* __restrict__ C, int M, int N, int K) {
    __shared__ ushort As[3 * A_TILE];   // 96 KB
    __shared__ ushort Bs[3 * B_TILE];   // 48 KB

    const int tid  = threadIdx.x;
    const int wid  = tid >> 6;
    const int lane = tid & 63;

    // bijective XCD-aware block swizzle (m204)
    const int nwg  = (int)gridDim.x;
    const int orig = (int)blockIdx.x;
    const int q = nwg >> 3, rr = nwg & 7;
    const int xcd = orig & 7;
    const int swz = ((xcd < rr) ? xcd * (q + 1) : rr * (q + 1) + (xcd - rr) * q)
                    + (orig >> 3);
    const int nTilesN = N / BN;
    const int brow = (swz / nTilesN) * BM;
    const int bcol = (swz % nTilesN) * BN;

    // 8 waves = 4M x 2N, each owns a 64x64 output sub-tile
    const int wr = (wid >> 1) * 64;
    const int wc = (wid & 1) * 64;
    const int fr = lane & 15;
    const int hi = lane >> 4;

    // fragment LDS offsets (ushort units), loop-invariant, swizzled
    int offA[2][4], offB[2][4];
#pragma unroll
    for (int s = 0; s < 2; ++s) {
#pragma unroll
        for (int m = 0; m < 4; ++m) {
            int row = wr + m * 16 + fr;                  // row&7 == fr&7
            offA[s][m] = row * BK + (((s * 4 + hi) ^ (fr & 7)) * 8);
        }
#pragma unroll
        for (int n = 0; n < 4; ++n) {
            int row = wc + n * 16 + fr;
            offB[s][n] = row * BK + (((s * 4 + hi) ^ (fr & 7)) * 8);
        }
    }

    // staging: row_in_round = wid*8 + lane/8, source chunk pre-swizzled
    const int srow = wid * 8 + (lane >> 3);
    const int scol = ((lane & 7) ^ (lane >> 3)) * 8;
    const ushort* aSrc = A + (size_t)(brow + srow) * K + scol;
    const ushort* bSrc = B + (size_t)(bcol + srow) * K + scol;
    const int stDst = wid * 512;   // wave-uniform LDS chunk (HW adds lane*16B)

    floatx4 acc[4][4];
#pragma unroll
    for (int m = 0; m < 4; ++m)
#pragma unroll
        for (int n = 0; n < 4; ++n) acc[m][n] = (floatx4)0.0f;

    auto STAGE = [&](int koff, int bufsel) {
        ushort* da = As + bufsel * A_TILE + stDst;
        ushort* db = Bs + bufsel * B_TILE + stDst;
        const ushort* sa = aSrc + koff;
        const ushort* sb = bSrc + koff;
        gload_lds16(sa,                   da);
        gload_lds16(sa + (size_t)64  * K, da + 4096);
        gload_lds16(sa + (size_t)128 * K, da + 8192);
        gload_lds16(sa + (size_t)192 * K, da + 12288);
        gload_lds16(sb,                   db);
        gload_lds16(sb + (size_t)64  * K, db + 4096);
    };

    auto LOADF = [&](int bufsel, int s, bf16x8 (&af)[4], bf16x8 (&bf)[4]) {
        const ushort* pA = As + bufsel * A_TILE;
        const ushort* pB = Bs + bufsel * B_TILE;
#pragma unroll
        for (int m = 0; m < 4; ++m) af[m] = *(const bf16x8*)(pA + offA[s][m]);
#pragma unroll
        for (int n = 0; n < 4; ++n) bf[n] = *(const bf16x8*)(pB + offB[s][n]);
    };

    auto DOMFMA = [&](bf16x8 (&af)[4], bf16x8 (&bf)[4]) {
        __builtin_amdgcn_s_setprio(1);
#pragma unroll
        for (int m = 0; m < 4; ++m)
#pragma unroll
            for (int n = 0; n < 4; ++n)
                acc[m][n] = __builtin_amdgcn_mfma_f32_16x16x32_bf16(
                    af[m], bf[n], acc[m][n], 0, 0, 0);
        __builtin_amdgcn_s_setprio(0);
    };

    const int nK = K / BK;   // caller guarantees >= 4

    bf16x8 afA[4], bfA[4];   // phase-0 fragment set
    bf16x8 afB[4], bfB[4];   // phase-1 fragment set

    STAGE(0, 0);
    STAGE(BK, 1);
    asm volatile("s_waitcnt vmcnt(6)" ::: "memory");   // tile 0 landed (own)
    __builtin_amdgcn_s_barrier();                      // all waves' tile 0
    asm volatile("" ::: "memory");
    LOADF(0, 0, afA, bfA);                             // frag(0,0)

    int cur = 0;
    for (int kt = 0; kt < nK; ++kt) {
        __builtin_amdgcn_s_barrier();                  // B1
        asm volatile("" ::: "memory");
        if (kt + 2 < nK) {
            int tgt = cur + 2; if (tgt >= 3) tgt -= 3;
            STAGE((kt + 2) * BK, tgt);                 // outstanding 6 -> 12
        }
        LOADF(cur, 1, afB, bfB);                       // issue frag(kt,1) reads
        DOMFMA(afA, bfA);                              // phase 0 (hides reads)
        if (kt + 1 < nK) {
            if (kt + 2 < nK)
                asm volatile("s_waitcnt vmcnt(6)" ::: "memory"); // kt+1 landed
            else
                asm volatile("s_waitcnt vmcnt(0)" ::: "memory"); // last tile
            __builtin_amdgcn_s_barrier();              // B2
            asm volatile("" ::: "memory");
            int nxt = cur + 1; if (nxt >= 3) nxt -= 3;
            LOADF(nxt, 0, afA, bfA);                   // issue frag(kt+1,0)
            cur = nxt;
        }
        DOMFMA(afB, bfB);                              // phase 1
    }

    // epilogue: C/D layout col=lane&15, row=hi*4+j  [m89/m91 verified]
    float al[4], bi[4];
    const int ccol = bcol + wc + fr;
#pragma unroll
    for (int n = 0; n < 4; ++n) {
        al[n] = alpha[ccol + n * 16];
        bi[n] = bias[ccol + n * 16];
    }
    const int r0 = brow + wr + hi * 4;
#pragma unroll
    for (int m = 0; m < 4; ++m)
#pragma unroll
        for (int n = 0; n < 4; ++n)
#pragma unroll
            for (int j = 0; j < 4; ++j) {
                int row = r0 + m * 16 + j;
                int col = ccol + n * 16;
                C[(size_t)row * N + col] = acc[m][n][j] * al[n] + bi[n];
            }
}

// ---------------- safety fallback (fp32 vector, naive) ----------------------
__global__ void gemm_f32_naive(const float* __restrict__ A,
                               const float* __restrict__ B,
                               const float* __restrict__ scale,
                               const float* __restrict__ mean,
                               const float* __restrict__ var,
                               const float* __restrict__ gamma,
                               const float* __restrict__ beta,
                               float* __restrict__ C, int N, int K) {
    int o = blockIdx.x * blockDim.x + threadIdx.x;
    int b = blockIdx.y;
    if (o >= N) return;
    float s = 0.f;
    const float* a = A + (size_t)b * K;
    const float* w = B + (size_t)o * K;
    for (int k = 0; k < K; ++k) s += a[k] * w[k];
    float rs = rsqrtf(var[o] + EPS);
    float g = gamma[o] * rs;
    C[(size_t)b * N + o] = s * scale[o] * g + (beta[o] - mean[o] * g);
}

extern "C" void kernel_launch(void* const* d_in, const int* in_sizes, int n_in,
                              void* d_out, int out_size, void* d_ws, size_t ws_size,
                              hipStream_t stream) {
    const float* x     = (const float*)d_in[0];
    const float* w     = (const float*)d_in[1];
    const float* scale = (const float*)d_in[2];
    const float* mean  = (const float*)d_in[3];
    const float* var   = (const float*)d_in[4];
    const float* gamma = (const float*)d_in[5];
    const float* beta  = (const float*)d_in[6];
    float* out = (float*)d_out;

    const int OUT = in_sizes[2];
    const int IN  = in_sizes[1] / OUT;
    const int Bsz = in_sizes[0] / IN;

    const size_t xElems = (size_t)Bsz * IN;
    const size_t wElems = (size_t)OUT * IN;
    const size_t need = xElems * 2 + wElems * 2 + (size_t)OUT * 8;

    const bool tiled_ok = (Bsz % BM == 0) && (OUT % BN == 0) &&
                          (IN % BK == 0) && (IN / BK >= 4) &&
                          (ws_size >= need);

    if (!tiled_ok) {
        dim3 grid((OUT + 255) / 256, Bsz);
        gemm_f32_naive<<<grid, 256, 0, stream>>>(x, w, scale, mean, var, gamma,
                                                 beta, out, OUT, IN);
        return;
    }

    ushort* xb = (ushort*)d_ws;
    ushort* wb = xb + xElems;
    float* alpha = (float*)(wb + wElems);
    float* bias  = alpha + OUT;

    cvt_f32_to_bf16<<<2048, 256, 0, stream>>>(x, xb, (int)(xElems / 4));
    cvt_f32_to_bf16<<<2048, 256, 0, stream>>>(w, wb, (int)(wElems / 4));
    bn_fold<<<(OUT + 255) / 256, 256, 0, stream>>>(scale, mean, var, gamma, beta,
                                                   alpha, bias, OUT);

    dim3 grid((Bsz / BM) * (OUT / BN));
    gemm_bf16_bn<<<grid, 512, 0, stream>>>(xb, wb, alpha, bias, out, Bsz, OUT, IN);
}

// Round 7
// 61.425 us; speedup vs baseline: 1.1282x; 1.1282x over previous
//
#include <hip/hip_runtime.h>
#include <hip/hip_bf16.h>

typedef __bf16 bf16x8 __attribute__((ext_vector_type(8)));
typedef float floatx4 __attribute__((ext_vector_type(4)));

#define BM 128
#define BN 128
#define BK 32
#define A_TILE (BM * BK)   // 4096 ushorts = 8 KB
#define B_TILE (BN * BK)   // 4096 ushorts = 8 KB
#define EPS 1e-5f

// ---------------- f32 -> bf16 conversion (vectorized, grid-stride) ----------
__global__ void cvt_f32_to_bf16(const float* __restrict__ in,
                                ushort* __restrict__ out, int n4) {
    int i = blockIdx.x * blockDim.x + threadIdx.x;
    int stride = gridDim.x * blockDim.x;
    for (; i < n4; i += stride) {
        float4 v = reinterpret_cast<const float4*>(in)[i];
        ushort4 o;
        o.x = __builtin_bit_cast(unsigned short, __float2bfloat16(v.x));
        o.y = __builtin_bit_cast(unsigned short, __float2bfloat16(v.y));
        o.z = __builtin_bit_cast(unsigned short, __float2bfloat16(v.z));
        o.w = __builtin_bit_cast(unsigned short, __float2bfloat16(v.w));
        reinterpret_cast<ushort4*>(out)[i] = o;
    }
}

// ---------------- fold BN+scale into per-column alpha/bias ------------------
__global__ void bn_fold(const float* __restrict__ scale,
                        const float* __restrict__ mean,
                        const float* __restrict__ var,
                        const float* __restrict__ gamma,
                        const float* __restrict__ beta,
                        float* __restrict__ alpha,
                        float* __restrict__ bias, int n) {
    int i = blockIdx.x * blockDim.x + threadIdx.x;
    if (i < n) {
        float rs = rsqrtf(var[i] + EPS);
        float g = gamma[i] * rs;
        alpha[i] = scale[i] * g;
        bias[i]  = beta[i] - mean[i] * g;
    }
}

__device__ __forceinline__ void gload_lds16(const ushort* g, ushort* l) {
    __builtin_amdgcn_global_load_lds(
        (const __attribute__((address_space(1))) void*)g,
        (__attribute__((address_space(3))) void*)l, 16, 0, 0);
}

// ---------------- bf16 MFMA GEMM: 128x128 tile, BK=32, depth-3, 2 blk/CU ----
// C[m][n] = sum_k A[m][k]*B[n][k]; epilogue C = C*alpha[n] + bias[n].
//
// R6 lesson: cross-phase restructure cut staging depth 3->2 and regressed
// (58.2 vs R4's 49.5 us). R4 lesson: a single barrier-locked block per CU
// serializes LDS-reads + MFMA + DMA (~3712 cyc/iter vs 1242 ideal). Fix here:
// SMALLER blocks (256 thr, 48 KB LDS) so grid=512 -> 2 blocks/CU; the CU
// scheduler overlaps one block's read/stage phase with the other's MFMA
// phase (m114 mechanism behind m97's 874 TF). Keep R4's proven depth-3
// lockstep skeleton: 3 LDS buffers, stage kt+3, counted vmcnt (4 loads/thread
// per tile -> steady 12 outstanding, retire to 8).
//
// LDS layout: [row][32] ushort, 64 B rows = 4 chunks of 16 B.
// Swizzle: phys_chunk = logical_chunk ^ ((row>>1)&3). Gives even bank-slot
// distribution for ds_read_b128 (2 lanes/slot per 16-lane group = free).
// Round-trip: DMA writes linearly (lane&3 = phys chunk), source column
// pre-swizzled by the same XOR; reads apply the XOR again (rule #21).
__global__ __launch_bounds__(256, 2) void gemm_bf16_bn(
    const ushort* __restrict__ A,   // [M][K] bf16 bits
    const ushort* __restrict__ B,   // [N][K] bf16 bits
    const float* __restrict__ alpha,
    const float* __restrict__ bias,
    float* __restrict__ C, int M, int N, int K) {
    __shared__ ushort As[3 * A_TILE];   // 24 KB
    __shared__ ushort Bs[3 * B_TILE];   // 24 KB

    const int tid  = threadIdx.x;
    const int wid  = tid >> 6;
    const int lane = tid & 63;

    // bijective XCD-aware block swizzle (m204)
    const int nwg  = (int)gridDim.x;
    const int orig = (int)blockIdx.x;
    const int q = nwg >> 3, rr = nwg & 7;
    const int xcd = orig & 7;
    const int swz = ((xcd < rr) ? xcd * (q + 1) : rr * (q + 1) + (xcd - rr) * q)
                    + (orig >> 3);
    const int nTilesN = N / BN;
    const int brow = (swz / nTilesN) * BM;
    const int bcol = (swz % nTilesN) * BN;

    // 4 waves = 2M x 2N, each owns a 64x64 output sub-tile
    const int wr = (wid >> 1) * 64;
    const int wc = (wid & 1) * 64;
    const int fr = lane & 15;
    const int hi = lane >> 4;   // fragment k-chunk index (16B units)

    // fragment LDS offsets (ushort units), loop-invariant, swizzled:
    // addr = row*32 + ((hi ^ ((row>>1)&3)) * 8;  row>>1&3 == fr>>1&3
    int offA[4], offB[4];
    const int pc = (hi ^ ((fr >> 1) & 3)) * 8;
#pragma unroll
    for (int m = 0; m < 4; ++m) offA[m] = (wr + m * 16 + fr) * BK + pc;
#pragma unroll
    for (int n = 0; n < 4; ++n) offB[n] = (wc + n * 16 + fr) * BK + pc;

    // staging: per 4 KB round (64 rows), thread t -> row t>>2, chunk t&3;
    // source chunk pre-swizzled: (t&3) ^ ((t>>3)&3)  (wave-local identical)
    const int srow = wid * 16 + (lane >> 2);
    const int scol = ((lane & 3) ^ ((lane >> 3) & 3)) * 8;
    const ushort* aSrc = A + (size_t)(brow + srow) * K + scol;
    const ushort* bSrc = B + (size_t)(bcol + srow) * K + scol;
    const int stDst = wid * 512;   // wave-uniform LDS base (HW adds lane*16B)

    floatx4 acc[4][4];
#pragma unroll
    for (int m = 0; m < 4; ++m)
#pragma unroll
        for (int n = 0; n < 4; ++n) acc[m][n] = (floatx4)0.0f;

    auto STAGE = [&](int koff, int bufsel) {
        ushort* da = As + bufsel * A_TILE + stDst;
        ushort* db = Bs + bufsel * B_TILE + stDst;
        const ushort* sa = aSrc + koff;
        const ushort* sb = bSrc + koff;
        gload_lds16(sa,                  da);
        gload_lds16(sa + (size_t)64 * K, da + 2048);
        gload_lds16(sb,                  db);
        gload_lds16(sb + (size_t)64 * K, db + 2048);
    };

    auto LOADF = [&](int bufsel, bf16x8 (&af)[4], bf16x8 (&bf)[4]) {
        const ushort* pA = As + bufsel * A_TILE;
        const ushort* pB = Bs + bufsel * B_TILE;
#pragma unroll
        for (int m = 0; m < 4; ++m) af[m] = *(const bf16x8*)(pA + offA[m]);
#pragma unroll
        for (int n = 0; n < 4; ++n) bf[n] = *(const bf16x8*)(pB + offB[n]);
    };

    auto DOMFMA = [&](bf16x8 (&af)[4], bf16x8 (&bf)[4]) {
        __builtin_amdgcn_s_setprio(1);
#pragma unroll
        for (int m = 0; m < 4; ++m)
#pragma unroll
            for (int n = 0; n < 4; ++n)
                acc[m][n] = __builtin_amdgcn_mfma_f32_16x16x32_bf16(
                    af[m], bf[n], acc[m][n], 0, 0, 0);
        __builtin_amdgcn_s_setprio(0);
    };

    const int nK = K / BK;   // caller guarantees >= 4

    STAGE(0, 0);
    STAGE(BK, 1);
    STAGE(2 * BK, 2);
    asm volatile("s_waitcnt vmcnt(8)" ::: "memory");    // tile 0 landed (own)
    __builtin_amdgcn_s_barrier();                       // all waves' tile 0
    asm volatile("" ::: "memory");

    int cur = 0;
    for (int kt = 0; kt < nK - 3; ++kt) {
        bf16x8 af[4], bf[4];
        LOADF(cur, af, bf);
        asm volatile("s_waitcnt lgkmcnt(0)" ::: "memory");  // own reads done
        __builtin_amdgcn_s_barrier();            // all waves done reading cur
        asm volatile("" ::: "memory");
        STAGE((kt + 3) * BK, cur);               // overwrite cur with tile kt+3
        DOMFMA(af, bf);
        asm volatile("s_waitcnt vmcnt(8)" ::: "memory");    // tile kt+1 landed
        __builtin_amdgcn_s_barrier();
        asm volatile("" ::: "memory");
        cur = (cur == 2) ? 0 : cur + 1;
    }
    // tail: tiles nK-3, nK-2, nK-1 (no more staging)
    {
        bf16x8 af[4], bf[4];
        LOADF(cur, af, bf);
        DOMFMA(af, bf);
        asm volatile("s_waitcnt vmcnt(4)" ::: "memory");    // tile nK-2 landed
        __builtin_amdgcn_s_barrier();
        asm volatile("" ::: "memory");
        cur = (cur == 2) ? 0 : cur + 1;
    }
    {
        bf16x8 af[4], bf[4];
        LOADF(cur, af, bf);
        DOMFMA(af, bf);
        asm volatile("s_waitcnt vmcnt(0)" ::: "memory");    // tile nK-1 landed
        __builtin_amdgcn_s_barrier();
        asm volatile("" ::: "memory");
        cur = (cur == 2) ? 0 : cur + 1;
    }
    {
        bf16x8 af[4], bf[4];
        LOADF(cur, af, bf);
        DOMFMA(af, bf);
    }

    // epilogue: C/D layout col=lane&15, row=hi*4+j  [m89/m91 verified]
    float al[4], bi[4];
    const int ccol = bcol + wc + fr;
#pragma unroll
    for (int n = 0; n < 4; ++n) {
        al[n] = alpha[ccol + n * 16];
        bi[n] = bias[ccol + n * 16];
    }
    const int r0 = brow + wr + hi * 4;
#pragma unroll
    for (int m = 0; m < 4; ++m)
#pragma unroll
        for (int n = 0; n < 4; ++n)
#pragma unroll
            for (int j = 0; j < 4; ++j) {
                int row = r0 + m * 16 + j;
                int col = ccol + n * 16;
                C[(size_t)row * N + col] = acc[m][n][j] * al[n] + bi[n];
            }
}

// ---------------- safety fallback (fp32 vector, naive) ----------------------
__global__ void gemm_f32_naive(const float* __restrict__ A,
                               const float* __restrict__ B,
                               const float* __restrict__ scale,
                               const float* __restrict__ mean,
                               const float* __restrict__ var,
                               const float* __restrict__ gamma,
                               const float* __restrict__ beta,
                               float* __restrict__ C, int N, int K) {
    int o = blockIdx.x * blockDim.x + threadIdx.x;
    int b = blockIdx.y;
    if (o >= N) return;
    float s = 0.f;
    const float* a = A + (size_t)b * K;
    const float* w = B + (size_t)o * K;
    for (int k = 0; k < K; ++k) s += a[k] * w[k];
    float rs = rsqrtf(var[o] + EPS);
    float g = gamma[o] * rs;
    C[(size_t)b * N + o] = s * scale[o] * g + (beta[o] - mean[o] * g);
}

extern "C" void kernel_launch(void* const* d_in, const int* in_sizes, int n_in,
                              void* d_out, int out_size, void* d_ws, size_t ws_size,
                              hipStream_t stream) {
    const float* x     = (const float*)d_in[0];
    const float* w     = (const float*)d_in[1];
    const float* scale = (const float*)d_in[2];
    const float* mean  = (const float*)d_in[3];
    const float* var   = (const float*)d_in[4];
    const float* gamma = (const float*)d_in[5];
    const float* beta  = (const float*)d_in[6];
    float* out = (float*)d_out;

    const int OUT = in_sizes[2];
    const int IN  = in_sizes[1] / OUT;
    const int Bsz = in_sizes[0] / IN;

    const size_t xElems = (size_t)Bsz * IN;
    const size_t wElems = (size_t)OUT * IN;
    const size_t need = xElems * 2 + wElems * 2 + (size_t)OUT * 8;

    const bool tiled_ok = (Bsz % BM == 0) && (OUT % BN == 0) &&
                          (IN % BK == 0) && (IN / BK >= 4) &&
                          (ws_size >= need);

    if (!tiled_ok) {
        dim3 grid((OUT + 255) / 256, Bsz);
        gemm_f32_naive<<<grid, 256, 0, stream>>>(x, w, scale, mean, var, gamma,
                                                 beta, out, OUT, IN);
        return;
    }

    ushort* xb = (ushort*)d_ws;
    ushort* wb = xb + xElems;
    float* alpha = (float*)(wb + wElems);
    float* bias  = alpha + OUT;

    cvt_f32_to_bf16<<<2048, 256, 0, stream>>>(x, xb, (int)(xElems / 4));
    cvt_f32_to_bf16<<<2048, 256, 0, stream>>>(w, wb, (int)(wElems / 4));
    bn_fold<<<(OUT + 255) / 256, 256, 0, stream>>>(scale, mean, var, gamma, beta,
                                                   alpha, bias, OUT);

    dim3 grid((Bsz / BM) * (OUT / BN));
    gemm_bf16_bn<<<grid, 256, 0, stream>>>(xb, wb, alpha, bias, out, Bsz, OUT, IN);
}

// Round 9
// 57.337 us; speedup vs baseline: 1.2086x; 1.0713x over previous
//
#include <hip/hip_runtime.h>
#include <hip/hip_bf16.h>

typedef __bf16 bf16x8 __attribute__((ext_vector_type(8)));
typedef float floatx4 __attribute__((ext_vector_type(4)));

#define BM 256
#define BN 128
#define BK 64
#define A_TILE (BM * BK)   // 16384 ushorts = 32 KB
#define B_TILE (BN * BK)   // 8192 ushorts  = 16 KB
#define EPS 1e-5f

// ---------------- f32 -> bf16 conversion (vectorized, grid-stride) ----------
__global__ void cvt_f32_to_bf16(const float* __restrict__ in,
                                ushort* __restrict__ out, int n4) {
    int i = blockIdx.x * blockDim.x + threadIdx.x;
    int stride = gridDim.x * blockDim.x;
    for (; i < n4; i += stride) {
        float4 v = reinterpret_cast<const float4*>(in)[i];
        ushort4 o;
        o.x = __builtin_bit_cast(unsigned short, __float2bfloat16(v.x));
        o.y = __builtin_bit_cast(unsigned short, __float2bfloat16(v.y));
        o.z = __builtin_bit_cast(unsigned short, __float2bfloat16(v.z));
        o.w = __builtin_bit_cast(unsigned short, __float2bfloat16(v.w));
        reinterpret_cast<ushort4*>(out)[i] = o;
    }
}

// ---------------- fold BN+scale into per-column alpha/bias ------------------
__global__ void bn_fold(const float* __restrict__ scale,
                        const float* __restrict__ mean,
                        const float* __restrict__ var,
                        const float* __restrict__ gamma,
                        const float* __restrict__ beta,
                        float* __restrict__ alpha,
                        float* __restrict__ bias, int n) {
    int i = blockIdx.x * blockDim.x + threadIdx.x;
    if (i < n) {
        float rs = rsqrtf(var[i] + EPS);
        float g = gamma[i] * rs;
        alpha[i] = scale[i] * g;
        bias[i]  = beta[i] - mean[i] * g;
    }
}

__device__ __forceinline__ void gload_lds16(const ushort* g, ushort* l) {
    __builtin_amdgcn_global_load_lds(
        (const __attribute__((address_space(1))) void*)g,
        (__attribute__((address_space(3))) void*)l, 16, 0, 0);
}

// ---------------- bf16 MFMA GEMM: 256x128, BK=64, fine 2-phase/K-tile -------
// C[m][n] = sum_k A[m][k]*B[n][k]; epilogue C = C*alpha[n] + bias[n].
//
// R4/R7 post-mortem: coarse {all ds_read -> barrier -> all MFMA} lockstep
// serializes LDS-read time and MFMA time (928 cyc per BK=32 step vs 310 of
// MFMA). m201/m233 gate: the fix is FINE phases where read-issue, staging
// and MFMA interleave across waves. Structure per K-tile t (cur = t%3):
//   phase s=0,1:
//     8 x ds_read_b128  (frags of kstep s, buf cur)   // compiler lgkm-guards
//     3 x global_load_lds (tile t+2 -> buf (t+2)%3)   // never a live buffer
//     s_barrier                                       // phase alignment
//     setprio(1); 16 x MFMA(kstep s); setprio(0)      // waves pipeline: first
//     s_barrier                                       //  finisher MFMAs while
//                                                     //  others' reads return
//   tile end (inside phase 1, before last barrier):
//     s_waitcnt vmcnt(6)   // own 6 loads of tile t+1 landed; t+2's in flight
// The barrier AFTER vmcnt gives the cross-wave guarantee (every wave passed
// its own vmcnt => whole tile t+1 resident).
// Depth: stage t+2 while reading t => issue-to-use gap ~2 K-tile times.
// vmcnt: steady outstanding = 6 (t+1) + 3 (t+2, ph0) + 3 (ph1) -> retire to 6.
//
// LDS swizzle (T2, rule #21 both-sides): phys chunk = logical chunk ^ (row&7),
// pre-swizzled on the global source, same XOR on reads. R2/R4: conflicts = 0.
__global__ __launch_bounds__(512, 2) void gemm_bf16_bn(
    const ushort* __restrict__ A,   // [M][K] bf16 bits
    const ushort* __restrict__ B,   // [N][K] bf16 bits
    const float* __restrict__ alpha,
    const float* __restrict__ bias,
    float* __restrict__ C, int M, int N, int K) {
    __shared__ ushort As[3 * A_TILE];   // 96 KB
    __shared__ ushort Bs[3 * B_TILE];   // 48 KB

    const int tid  = threadIdx.x;
    const int wid  = tid >> 6;
    const int lane = tid & 63;

    // bijective XCD-aware block swizzle (m204)
    const int nwg  = (int)gridDim.x;
    const int orig = (int)blockIdx.x;
    const int q = nwg >> 3, rr = nwg & 7;
    const int xcd = orig & 7;
    const int swz = ((xcd < rr) ? xcd * (q + 1) : rr * (q + 1) + (xcd - rr) * q)
                    + (orig >> 3);
    const int nTilesN = N / BN;
    const int brow = (swz / nTilesN) * BM;
    const int bcol = (swz % nTilesN) * BN;

    // 8 waves = 4M x 2N, each owns a 64x64 output sub-tile
    const int wr = (wid >> 1) * 64;
    const int wc = (wid & 1) * 64;
    const int fr = lane & 15;
    const int hi = lane >> 4;

    // fragment LDS offsets (ushort units), loop-invariant, swizzled
    int offA[2][4], offB[2][4];
#pragma unroll
    for (int s = 0; s < 2; ++s) {
#pragma unroll
        for (int m = 0; m < 4; ++m) {
            int row = wr + m * 16 + fr;                  // row&7 == fr&7
            offA[s][m] = row * BK + (((s * 4 + hi) ^ (fr & 7)) * 8);
        }
#pragma unroll
        for (int n = 0; n < 4; ++n) {
            int row = wc + n * 16 + fr;
            offB[s][n] = row * BK + (((s * 4 + hi) ^ (fr & 7)) * 8);
        }
    }

    // staging: per 8 KB round (64 rows), thread t -> row t>>3, chunk t&7;
    // source chunk pre-swizzled: (lane&7) ^ (lane>>3)  [row&7 == lane>>3]
    const int srow = wid * 8 + (lane >> 3);
    const int scol = ((lane & 7) ^ (lane >> 3)) * 8;
    const ushort* aSrc = A + (size_t)(brow + srow) * K + scol;
    const ushort* bSrc = B + (size_t)(bcol + srow) * K + scol;
    const int stDst = wid * 512;   // wave-uniform LDS base (HW adds lane*16B)

    floatx4 acc[4][4];
#pragma unroll
    for (int m = 0; m < 4; ++m)
#pragma unroll
        for (int n = 0; n < 4; ++n) acc[m][n] = (floatx4)0.0f;

    // staging halves: ph0 = A rounds 0..2, ph1 = A round 3 + B rounds 0..1
    auto STAGE_P0 = [&](int koff, int bufsel) {
        ushort* da = As + bufsel * A_TILE + stDst;
        const ushort* sa = aSrc + koff;
        gload_lds16(sa,                   da);
        gload_lds16(sa + (size_t)64  * K, da + 4096);
        gload_lds16(sa + (size_t)128 * K, da + 8192);
    };
    auto STAGE_P1 = [&](int koff, int bufsel) {
        ushort* da = As + bufsel * A_TILE + stDst;
        ushort* db = Bs + bufsel * B_TILE + stDst;
        const ushort* sa = aSrc + koff;
        const ushort* sb = bSrc + koff;
        gload_lds16(sa + (size_t)192 * K, da + 12288);
        gload_lds16(sb,                   db);
        gload_lds16(sb + (size_t)64  * K, db + 4096);
    };

    auto LOADF = [&](int bufsel, int s, bf16x8 (&af)[4], bf16x8 (&bf)[4]) {
        const ushort* pA = As + bufsel * A_TILE;
        const ushort* pB = Bs + bufsel * B_TILE;
#pragma unroll
        for (int m = 0; m < 4; ++m) af[m] = *(const bf16x8*)(pA + offA[s][m]);
#pragma unroll
        for (int n = 0; n < 4; ++n) bf[n] = *(const bf16x8*)(pB + offB[s][n]);
    };

    auto DOMFMA = [&](bf16x8 (&af)[4], bf16x8 (&bf)[4]) {
        __builtin_amdgcn_s_setprio(1);
#pragma unroll
        for (int m = 0; m < 4; ++m)
#pragma unroll
            for (int n = 0; n < 4; ++n)
                acc[m][n] = __builtin_amdgcn_mfma_f32_16x16x32_bf16(
                    af[m], bf[n], acc[m][n], 0, 0, 0);
        __builtin_amdgcn_s_setprio(0);
    };

    const int nK = K / BK;   // caller guarantees >= 4

    STAGE_P0(0, 0);  STAGE_P1(0, 0);
    STAGE_P0(BK, 1); STAGE_P1(BK, 1);
    asm volatile("s_waitcnt vmcnt(6)" ::: "memory");   // tile 0 landed (own)
    __builtin_amdgcn_s_barrier();                      // all waves' tile 0
    asm volatile("" ::: "memory");

    int cur = 0;
    for (int kt = 0; kt < nK; ++kt) {
        int tgt = cur + 2; if (tgt >= 3) tgt -= 3;
        const bool st = (kt + 2 < nK);
        bf16x8 af[4], bf[4];
        // ---- phase 0 ----
        LOADF(cur, 0, af, bf);
        if (st) STAGE_P0((kt + 2) * BK, tgt);
        asm volatile("" ::: "memory");
        __builtin_amdgcn_s_barrier();
        asm volatile("" ::: "memory");
        DOMFMA(af, bf);                     // compiler lgkm-guards af/bf
        asm volatile("" ::: "memory");
        __builtin_amdgcn_s_barrier();
        asm volatile("" ::: "memory");
        // ---- phase 1 ----
        LOADF(cur, 1, af, bf);
        if (st) STAGE_P1((kt + 2) * BK, tgt);
        asm volatile("" ::: "memory");
        __builtin_amdgcn_s_barrier();
        asm volatile("" ::: "memory");
        DOMFMA(af, bf);
        // ---- tile boundary: next tile resident? ----
        if (kt + 1 < nK) {
            if (st) asm volatile("s_waitcnt vmcnt(6)" ::: "memory");
            else    asm volatile("s_waitcnt vmcnt(0)" ::: "memory");
        }
        asm volatile("" ::: "memory");
        __builtin_amdgcn_s_barrier();
        asm volatile("" ::: "memory");
        cur = cur + 1; if (cur >= 3) cur = 0;
    }

    // epilogue: C/D layout col=lane&15, row=hi*4+j  [m89/m91 verified]
    float al[4], bi[4];
    const int ccol = bcol + wc + fr;
#pragma unroll
    for (int n = 0; n < 4; ++n) {
        al[n] = alpha[ccol + n * 16];
        bi[n] = bias[ccol + n * 16];
    }
    const int r0 = brow + wr + hi * 4;
#pragma unroll
    for (int m = 0; m < 4; ++m)
#pragma unroll
        for (int n = 0; n < 4; ++n)
#pragma unroll
            for (int j = 0; j < 4; ++j) {
                int row = r0 + m * 16 + j;
                int col = ccol + n * 16;
                C[(size_t)row * N + col] = acc[m][n][j] * al[n] + bi[n];
            }
}

// ---------------- safety fallback (fp32 vector, naive) ----------------------
__global__ void gemm_f32_naive(const float* __restrict__ A,
                               const float* __restrict__ B,
                               const float* __restrict__ scale,
                               const float* __restrict__ mean,
                               const float* __restrict__ var,
                               const float* __restrict__ gamma,
                               const float* __restrict__ beta,
                               float* __restrict__ C, int N, int K) {
    int o = blockIdx.x * blockDim.x + threadIdx.x;
    int b = blockIdx.y;
    if (o >= N) return;
    float s = 0.f;
    const float* a = A + (size_t)b * K;
    const float* w = B + (size_t)o * K;
    for (int k = 0; k < K; ++k) s += a[k] * w[k];
    float rs = rsqrtf(var[o] + EPS);
    float g = gamma[o] * rs;
    C[(size_t)b * N + o] = s * scale[o] * g + (beta[o] - mean[o] * g);
}

extern "C" void kernel_launch(void* const* d_in, const int* in_sizes, int n_in,
                              void* d_out, int out_size, void* d_ws, size_t ws_size,
                              hipStream_t stream) {
    const float* x     = (const float*)d_in[0];
    const float* w     = (const float*)d_in[1];
    const float* scale = (const float*)d_in[2];
    const float* mean  = (const float*)d_in[3];
    const float* var   = (const float*)d_in[4];
    const float* gamma = (const float*)d_in[5];
    const float* beta  = (const float*)d_in[6];
    float* out = (float*)d_out;

    const int OUT = in_sizes[2];
    const int IN  = in_sizes[1] / OUT;
    const int Bsz = in_sizes[0] / IN;

    const size_t xElems = (size_t)Bsz * IN;
    const size_t wElems = (size_t)OUT * IN;
    const size_t need = xElems * 2 + wElems * 2 + (size_t)OUT * 8;

    const bool tiled_ok = (Bsz % BM == 0) && (OUT % BN == 0) &&
                          (IN % BK == 0) && (IN / BK >= 4) &&
                          (ws_size >= need);

    if (!tiled_ok) {
        dim3 grid((OUT + 255) / 256, Bsz);
        gemm_f32_naive<<<grid, 256, 0, stream>>>(x, w, scale, mean, var, gamma,
                                                 beta, out, OUT, IN);
        return;
    }

    ushort* xb = (ushort*)d_ws;
    ushort* wb = xb + xElems;
    float* alpha = (float*)(wb + wElems);
    float* bias  = alpha + OUT;

    cvt_f32_to_bf16<<<2048, 256, 0, stream>>>(x, xb, (int)(xElems / 4));
    cvt_f32_to_bf16<<<2048, 256, 0, stream>>>(w, wb, (int)(wElems / 4));
    bn_fold<<<(OUT + 255) / 256, 256, 0, stream>>>(scale, mean, var, gamma, beta,
                                                   alpha, bias, OUT);

    dim3 grid((Bsz / BM) * (OUT / BN));
    gemm_bf16_bn<<<grid, 512, 0, stream>>>(xb, wb, alpha, bias, out, Bsz, OUT, IN);
}